// Round 6
// baseline (261.441 us; speedup 1.0000x reference)
//
#include <hip/hip_runtime.h>
#include <math.h>

typedef unsigned short u16;
typedef __bf16 bf16_t;
typedef bf16_t bf16x4 __attribute__((ext_vector_type(4)));
typedef bf16_t bf16x8 __attribute__((ext_vector_type(8)));
typedef short s16x4 __attribute__((ext_vector_type(4)));
typedef float f32x4 __attribute__((ext_vector_type(4)));

typedef const __attribute__((address_space(1))) void* gcp;
typedef __attribute__((address_space(3))) void* lcp;

#define BB 4
#define NN 2048
#define CC 512
#define HH 8
#define HD 64
#define HIDE_ 2048
#define TT (BB*NN)  // 8192

#if __has_builtin(__builtin_amdgcn_exp2f)
#define EXP2(x) __builtin_amdgcn_exp2f(x)
#else
#define EXP2(x) __expf((x) * 0.69314718055994531f)
#endif

#if __has_builtin(__builtin_amdgcn_rcpf)
#define RCP(x) __builtin_amdgcn_rcpf(x)
#else
#define RCP(x) (1.0f / (x))
#endif

__device__ __forceinline__ u16 f2bf(float f) {
  unsigned u = __float_as_uint(f);
  u += 0x7FFF + ((u >> 16) & 1);   // RNE
  return (u16)(u >> 16);
}

// bijective XCD-aware block swizzle (requires nwg % 8 == 0)
__device__ __forceinline__ int xcd_swz(int orig, int nwg) {
  return (orig & 7) * (nwg >> 3) + (orig >> 3);
}

__device__ __forceinline__ void bf8_to_f(const u16* p, float* f) {
  uint4 u = *(const uint4*)p;
  f[0] = __uint_as_float(u.x << 16); f[1] = __uint_as_float(u.x & 0xffff0000u);
  f[2] = __uint_as_float(u.y << 16); f[3] = __uint_as_float(u.y & 0xffff0000u);
  f[4] = __uint_as_float(u.z << 16); f[5] = __uint_as_float(u.z & 0xffff0000u);
  f[6] = __uint_as_float(u.w << 16); f[7] = __uint_as_float(u.w & 0xffff0000u);
}

// load 8 fp32, scale, pack to bf16x8
__device__ __forceinline__ bf16x8 ldq8(const float* p, float s) {
  float4 a = *(const float4*)p;
  float4 b = *(const float4*)(p + 4);
  bf16x8 r = {(bf16_t)(a.x * s), (bf16_t)(a.y * s), (bf16_t)(a.z * s), (bf16_t)(a.w * s),
              (bf16_t)(b.x * s), (bf16_t)(b.y * s), (bf16_t)(b.z * s), (bf16_t)(b.w * s)};
  return r;
}

// tanh-form GELU
__device__ __forceinline__ float gelu_tanh(float x) {
  float y = 0.7978845608028654f * x * (1.0f + 0.044715f * x * x);
  float a = y * 2.8853900817779268f;
  a = fminf(fmaxf(a, -30.0f), 30.0f);
  float e = EXP2(a);
  float t = (e - 1.0f) * RCP(e + 1.0f);
  return 0.5f * x * (1.0f + t);
}

// ---------------- prep: k/fc1_w/fc2_w cvt + V^T transpose ----------------
__global__ __launch_bounds__(256) void prep_kernel(const float* __restrict__ k,
                                                   const float* __restrict__ fc1w,
                                                   const float* __restrict__ fc2w,
                                                   const float* __restrict__ v,
                                                   u16* __restrict__ kb,
                                                   u16* __restrict__ w1b,
                                                   u16* __restrict__ w2b,
                                                   u16* __restrict__ vtb) {
  __shared__ __align__(16) u16 T[64 * 72];
  int bid = blockIdx.x, tid = threadIdx.x;
  if (bid < 3072) {
    const float* in;
    u16* out;
    int rel;
    if (bid < 2048)      { in = k;    out = kb;  rel = bid; }
    else if (bid < 2560) { in = fc1w; out = w1b; rel = bid - 2048; }
    else                 { in = fc2w; out = w2b; rel = bid - 2560; }
    int i = (rel * 256 + tid) * 8;
    float4 a = *(const float4*)(in + i);
    float4 b2 = *(const float4*)(in + i + 4);
    u16 r[8] = {f2bf(a.x), f2bf(a.y), f2bf(a.z), f2bf(a.w),
                f2bf(b2.x), f2bf(b2.y), f2bf(b2.z), f2bf(b2.w)};
    *(uint4*)(out + i) = *(const uint4*)r;
    return;
  }
  int tv = bid - 3072;
  int j0 = (tv & 31) * 64;
  int bh = tv >> 5;
  int b = bh >> 3, h = bh & 7;
#pragma unroll
  for (int i = 0; i < 16; i++) {
    int idx = i * 256 + tid;
    int j = idx >> 6, d = idx & 63;
    T[d * 72 + j] = f2bf(v[((size_t)(b * NN + j0 + j)) * CC + h * 64 + d]);
  }
  __syncthreads();
#pragma unroll
  for (int i = 0; i < 16; i++) {
    int idx = i * 256 + tid;
    int d = idx >> 6, j = idx & 63;
    vtb[((size_t)(bh * 64 + d)) * NN + j0 + j] = T[d * 72 + j];
  }
}

// ---------------- flash attention: dual-Q-group (32 q/wave), split-K halves ----------------
// v5: KVBLK=128 (8 tiles instead of 16) — halves barrier pairs, drains, loop overhead.
// Ks[128][64] key-major; Vs[64][128] d-major (16 col-blocks, XOR-swizzle in low 3 bits,
// pre-swizzled per-lane global source + linear LDS dest).
__global__ __launch_bounds__(256, 4) void attn_kernel(const float* __restrict__ qf,
                                                      const u16* __restrict__ kb,
                                                      const u16* __restrict__ vtb,
                                                      u16* __restrict__ ou,
                                                      float* __restrict__ lsum,
                                                      float qs) {
  __shared__ __align__(16) u16 Ks[128 * 64];
  __shared__ __align__(16) u16 Vs[64 * 128];
  int tid = threadIdx.x, wave = tid >> 6, lane = tid & 63;
  int l15 = lane & 15, quad = lane >> 4;
  int r7 = l15 & 7;
  int bid = xcd_swz(blockIdx.x, 512);
  int half = blockIdx.y;
  int qt = bid & 15, h = (bid >> 4) & 7, b = bid >> 7;
  int qw = qt * 128 + wave * 32;
  int j0base = half * 1024;

  u16* ou_ = ou + (size_t)half * TT * CC;
  float* ls_ = lsum + (size_t)half * TT * HH;

  const float* qp = qf + ((size_t)(b * NN + qw + l15)) * CC + h * 64 + quad * 8;
  bf16x8 qfA0 = ldq8(qp, qs);
  bf16x8 qfA1 = ldq8(qp + 32, qs);
  bf16x8 qfB0 = ldq8(qp + (size_t)16 * CC, qs);
  bf16x8 qfB1 = ldq8(qp + (size_t)16 * CC + 32, qs);

  // K staging: rows rK = wave*32 + rl + {0,8,16,24}; colblock cb = (lane&7)^rl
  int rl = lane >> 3;
  int cb = (lane & 7) ^ rl;
  int rK = wave * 32 + rl;
  const u16* kp = kb + ((size_t)(b * NN + j0base + rK)) * CC + h * 64 + cb * 8;
  // V staging: d-rows rV = wave*16 + i*4 + (lane>>4); 256B rows; swizzle ^(rV&7)
  int rv4 = lane >> 4;            // 0..3 (row within each 4-row load)
  int sv = (lane & 15) ^ rv4;     // source colblock for even i (rV&7 = rv4)
  size_t vtbase = ((size_t)(b * HH + h)) * 64 * NN;
  const u16* vpE = vtb + vtbase + (size_t)(wave * 16 + rv4) * NN + j0base + sv * 8;
  const u16* vpO = vtb + vtbase + (size_t)(wave * 16 + rv4) * NN + j0base + (sv ^ 4) * 8;

  float lA = 0.f, lB = 0.f;
  f32x4 oA[4] = {}, oB[4] = {};

  for (int kt = 0; kt < 8; kt++) {
    __syncthreads();
#pragma unroll
    for (int i = 0; i < 4; i++)
      __builtin_amdgcn_global_load_lds((gcp)(kp + (size_t)(i * 8) * CC),
          (lcp)&Ks[(wave * 32 + i * 8) * 64], 16, 0, 0);
#pragma unroll
    for (int i = 0; i < 4; i++) {
      const u16* vp = (i & 1) ? vpO : vpE;
      __builtin_amdgcn_global_load_lds((gcp)(vp + (size_t)(i * 4) * NN),
          (lcp)&Vs[(wave * 16 + i * 4) * 128], 16, 0, 0);
    }
    kp += (size_t)128 * CC;
    vpE += 128; vpO += 128;
    __syncthreads();

    s16x4 pfA[8], pfB[8];
    __builtin_amdgcn_s_setprio(1);
#pragma unroll
    for (int nt = 0; nt < 8; nt++) {
      const u16* krow = &Ks[(nt * 16 + l15) * 64];
      bf16x8 k0 = *(const bf16x8*)&krow[(quad ^ r7) * 8];
      bf16x8 k1 = *(const bf16x8*)&krow[((quad + 4) ^ r7) * 8];
      f32x4 zA = {0.f, 0.f, 0.f, 0.f}, zB = {0.f, 0.f, 0.f, 0.f};
      zA = __builtin_amdgcn_mfma_f32_16x16x32_bf16(k0, qfA0, zA, 0, 0, 0);
      zA = __builtin_amdgcn_mfma_f32_16x16x32_bf16(k1, qfA1, zA, 0, 0, 0);
      zB = __builtin_amdgcn_mfma_f32_16x16x32_bf16(k0, qfB0, zB, 0, 0, 0);
      zB = __builtin_amdgcn_mfma_f32_16x16x32_bf16(k1, qfB1, zB, 0, 0, 0);
      float a0 = EXP2(zA[0]), a1 = EXP2(zA[1]), a2 = EXP2(zA[2]), a3 = EXP2(zA[3]);
      float b0 = EXP2(zB[0]), b1 = EXP2(zB[1]), b2 = EXP2(zB[2]), b3 = EXP2(zB[3]);
      lA += (a0 + a1) + (a2 + a3);
      lB += (b0 + b1) + (b2 + b3);
      bf16x4 ta = {(bf16_t)a0, (bf16_t)a1, (bf16_t)a2, (bf16_t)a3};
      bf16x4 tb = {(bf16_t)b0, (bf16_t)b1, (bf16_t)b2, (bf16_t)b3};
      pfA[nt] = __builtin_bit_cast(s16x4, ta);
      pfB[nt] = __builtin_bit_cast(s16x4, tb);
    }
#pragma unroll
    for (int dt = 0; dt < 4; dt++) {
      const u16* vrow = &Vs[(dt * 16 + l15) * 128];
#pragma unroll
      for (int nt = 0; nt < 8; nt++) {
        s16x4 vf = *(const s16x4*)
            &vrow[((nt * 2 + (quad >> 1)) ^ r7) * 8 + (quad & 1) * 4];
        oA[dt] = __builtin_amdgcn_mfma_f32_16x16x16bf16_1k(vf, pfA[nt], oA[dt], 0, 0, 0);
        oB[dt] = __builtin_amdgcn_mfma_f32_16x16x16bf16_1k(vf, pfB[nt], oB[dt], 0, 0, 0);
      }
    }
    __builtin_amdgcn_s_setprio(0);
  }

  lA += __shfl_xor(lA, 16, 64);
  lA += __shfl_xor(lA, 32, 64);
  lB += __shfl_xor(lB, 16, 64);
  lB += __shfl_xor(lB, 32, 64);
  if (quad == 0) {
    ls_[(size_t)(b * NN + qw + l15) * HH + h] = lA;
    ls_[(size_t)(b * NN + qw + 16 + l15) * HH + h] = lB;
  }
  size_t obase = ((size_t)(b * NN + qw + l15)) * CC + h * 64 + quad * 4;
#pragma unroll
  for (int dt = 0; dt < 4; dt++) {
    u16 ra[4] = {f2bf(oA[dt][0]), f2bf(oA[dt][1]), f2bf(oA[dt][2]), f2bf(oA[dt][3])};
    u16 rb[4] = {f2bf(oB[dt][0]), f2bf(oB[dt][1]), f2bf(oB[dt][2]), f2bf(oB[dt][3])};
    *(uint2*)&ou_[obase + dt * 16] = *(const uint2*)ra;
    *(uint2*)&ou_[obase + (size_t)16 * CC + dt * 16] = *(const uint2*)rb;
  }
}

// ---------------- ln1: combine bf16 O_u halves + fp32 q residual + LN -> bf16 ----------------
__global__ __launch_bounds__(256) void ln1_kernel(const float* __restrict__ q,
                                                  const u16* __restrict__ ou,
                                                  const float* __restrict__ lsum,
                                                  const float* __restrict__ w,
                                                  const float* __restrict__ bb,
                                                  u16* __restrict__ outb) {
  int tid = threadIdx.x;
  int row = blockIdx.x * 4 + (tid >> 6);
  int lane = tid & 63;
  int h = lane >> 3;
  size_t base = (size_t)row * CC + lane * 8;
  const u16* ou1 = ou + (size_t)TT * CC;
  const float* ls1 = lsum + (size_t)TT * HH;
  float li = lsum[(size_t)row * HH + h] + ls1[(size_t)row * HH + h];
  float inv = 1.0f / li;
  float4 a0 = *(const float4*)(q + base);
  float4 a1 = *(const float4*)(q + base + 4);
  float c[8], d[8];
  bf8_to_f(ou + base, c);
  bf8_to_f(ou1 + base, d);
  float av[8] = {a0.x, a0.y, a0.z, a0.w, a1.x, a1.y, a1.z, a1.w};
  float x[8];
#pragma unroll
  for (int i = 0; i < 8; i++) x[i] = av[i] + (c[i] + d[i]) * inv;
  float sum = 0.f, sq = 0.f;
#pragma unroll
  for (int i = 0; i < 8; i++) { sum += x[i]; sq += x[i] * x[i]; }
#pragma unroll
  for (int msk = 1; msk < 64; msk <<= 1) {
    sum += __shfl_xor(sum, msk, 64);
    sq += __shfl_xor(sq, msk, 64);
  }
  float mu = sum * (1.0f / CC);
  float var = sq * (1.0f / CC) - mu * mu;
  float rs = rsqrtf(var + 1e-6f);
  int col = lane * 8;
  float4 w0 = *(const float4*)(w + col);
  float4 w1 = *(const float4*)(w + col + 4);
  float4 b0 = *(const float4*)(bb + col);
  float4 b1 = *(const float4*)(bb + col + 4);
  float wv[8] = {w0.x, w0.y, w0.z, w0.w, w1.x, w1.y, w1.z, w1.w};
  float bv[8] = {b0.x, b0.y, b0.z, b0.w, b1.x, b1.y, b1.z, b1.w};
  u16 r[8];
#pragma unroll
  for (int i = 0; i < 8; i++) r[i] = f2bf((x[i] - mu) * rs * wv[i] + bv[i]);
  *(uint4*)(outb + base) = *(const uint4*)r;
}

// ---------------- ln2: bf16 residual + bf16 split-K partials (x4) + bias + LN ----------------
__global__ __launch_bounds__(256) void ln2_kernel(const u16* __restrict__ q2b,
                                                  const u16* __restrict__ mp,
                                                  const float* __restrict__ fb,
                                                  const float* __restrict__ w,
                                                  const float* __restrict__ bb,
                                                  float* __restrict__ outf) {
  int tid = threadIdx.x;
  int row = blockIdx.x * 4 + (tid >> 6);
  int lane = tid & 63;
  size_t base = (size_t)row * CC + lane * 8;
  const u16* mp1 = mp + (size_t)TT * CC;
  const u16* mp2 = mp + (size_t)2 * TT * CC;
  const u16* mp3 = mp + (size_t)3 * TT * CC;
  int col = lane * 8;
  float a[8], c[8], d[8], e[8], g[8];
  bf8_to_f(q2b + base, a);
  bf8_to_f(mp + base, c);
  bf8_to_f(mp1 + base, d);
  bf8_to_f(mp2 + base, e);
  bf8_to_f(mp3 + base, g);
  float4 f0 = *(const float4*)(fb + col);
  float4 f1 = *(const float4*)(fb + col + 4);
  float fbv[8] = {f0.x, f0.y, f0.z, f0.w, f1.x, f1.y, f1.z, f1.w};
  float x[8];
#pragma unroll
  for (int i = 0; i < 8; i++) x[i] = a[i] + ((c[i] + d[i]) + (e[i] + g[i])) + fbv[i];
  float sum = 0.f, sq = 0.f;
#pragma unroll
  for (int i = 0; i < 8; i++) { sum += x[i]; sq += x[i] * x[i]; }
#pragma unroll
  for (int msk = 1; msk < 64; msk <<= 1) {
    sum += __shfl_xor(sum, msk, 64);
    sq += __shfl_xor(sq, msk, 64);
  }
  float mu = sum * (1.0f / CC);
  float var = sq * (1.0f / CC) - mu * mu;
  float rs = rsqrtf(var + 1e-6f);
  float4 w0 = *(const float4*)(w + col);
  float4 w1 = *(const float4*)(w + col + 4);
  float4 b0 = *(const float4*)(bb + col);
  float4 b1 = *(const float4*)(bb + col + 4);
  float wv[8] = {w0.x, w0.y, w0.z, w0.w, w1.x, w1.y, w1.z, w1.w};
  float bv[8] = {b0.x, b0.y, b0.z, b0.w, b1.x, b1.y, b1.z, b1.w};
  float y[8];
#pragma unroll
  for (int i = 0; i < 8; i++) y[i] = (x[i] - mu) * rs * wv[i] + bv[i];
  *(float4*)(outf + base) = make_float4(y[0], y[1], y[2], y[3]);
  *(float4*)(outf + base + 4) = make_float4(y[4], y[5], y[6], y[7]);
}

// ---------------- GEMM 256x256 tile, BK=64, 8 waves, dbuf LDS + counted-vmcnt phases ----------------
#define GBAR() do { asm volatile("" ::: "memory"); __builtin_amdgcn_s_barrier(); \
                    asm volatile("" ::: "memory"); } while (0)

template <bool GELU>
__global__ __launch_bounds__(512, 2) void gemm256(const u16* __restrict__ A,
                                                  const u16* __restrict__ Bw,
                                                  const float* __restrict__ bias,
                                                  u16* __restrict__ outb,
                                                  int Nn, int K, int NT,
                                                  int gx, int gy) {
  __shared__ __align__(16) u16 As[2][256 * 64];
  __shared__ __align__(16) u16 Bs[2][256 * 64];
  int tid = threadIdx.x, wave = tid >> 6, lane = tid & 63;
  int l15 = lane & 15, quad = lane >> 4;
  int r7x = l15 & 7;
  int nwg = gridDim.x;
  int l = xcd_swz(blockIdx.x, nwg);
  int bx = l % gx;
  int by = (l / gx) % gy;
  int bz = l / (gx * gy);
  int m0 = by * 256, n0 = bx * 256;
  int kbeg = bz * (NT * 64);
  u16* outz = outb + (size_t)bz * ((size_t)TT * CC);
  int wm = (wave >> 2) * 128, wn = (wave & 3) * 64;
  int rl = lane >> 3;
  int cb = (lane & 7) ^ rl;
  const size_t rowK8 = (size_t)8 * K, rowK128 = (size_t)128 * K;
  const u16* Ap = &A[(size_t)(m0 + wave * 16 + rl) * K + kbeg + cb * 8];
  const u16* Bp = &Bw[(size_t)(n0 + wave * 16 + rl) * K + kbeg + cb * 8];
  unsigned sbase = wave * 16 * 64;

  f32x4 acc[8][4] = {};

  auto stageA = [&](int buf, int kofs) {
#pragma unroll
    for (int half = 0; half < 2; half++) {
      const u16* p = Ap + kofs + (size_t)half * rowK128;
      __builtin_amdgcn_global_load_lds((gcp)p, (lcp)&As[buf][half * 8192 + sbase], 16, 0, 0);
      __builtin_amdgcn_global_load_lds((gcp)(p + rowK8), (lcp)&As[buf][half * 8192 + sbase + 512], 16, 0, 0);
    }
  };
  auto stageB = [&](int buf, int kofs) {
#pragma unroll
    for (int half = 0; half < 2; half++) {
      const u16* p = Bp + kofs + (size_t)half * rowK128;
      __builtin_amdgcn_global_load_lds((gcp)p, (lcp)&Bs[buf][half * 8192 + sbase], 16, 0, 0);
      __builtin_amdgcn_global_load_lds((gcp)(p + rowK8), (lcp)&Bs[buf][half * 8192 + sbase + 512], 16, 0, 0);
    }
  };

  // prologue: prefetch K-tiles 0 and 1
  stageB(0, 0); stageA(0, 0);
  stageB(1, 64); stageA(1, 64);
  asm volatile("s_waitcnt vmcnt(8)" ::: "memory");
  __builtin_amdgcn_s_barrier();

#define RDA(buf, mfr, kh) \
  (*(const bf16x8*)&As[buf][(wm + (mfr) * 16 + l15) * 64 + (((kh) * 4 + quad) ^ r7x) * 8])
#define RDB(buf, nfr, kh) \
  (*(const bf16x8*)&Bs[buf][(wn + (nfr) * 16 + l15) * 64 + (((kh) * 4 + quad) ^ r7x) * 8])
#define QMFMA(AM0, BN0, AF, BF)                                              \
  _Pragma("unroll") for (int am = 0; am < 4; am++)                           \
  _Pragma("unroll") for (int bn = 0; bn < 2; bn++)                           \
  _Pragma("unroll") for (int kh = 0; kh < 2; kh++)                           \
    acc[(AM0) + am][(BN0) + bn] = __builtin_amdgcn_mfma_f32_16x16x32_bf16(   \
        AF[am][kh], BF[bn][kh], acc[(AM0) + am][(BN0) + bn], 0, 0, 0);

  for (int t = 0; t < NT; t++) {
    int buf = t & 1;
    int kof2 = (t + 2) * 64;
    bool pf = (t + 2) < NT;
    bf16x8 aF[4][2], bLo[2][2], bHi[2][2];
    // ---- P1
#pragma unroll
    for (int am = 0; am < 4; am++)
#pragma unroll
      for (int kh = 0; kh < 2; kh++) aF[am][kh] = RDA(buf, am, kh);
#pragma unroll
    for (int bn = 0; bn < 2; bn++)
#pragma unroll
      for (int kh = 0; kh < 2; kh++) bLo[bn][kh] = RDB(buf, bn, kh);
    __builtin_amdgcn_s_setprio(1);
    QMFMA(0, 0, aF, bLo)
    __builtin_amdgcn_s_setprio(0);
    GBAR();
    // ---- P2
#pragma unroll
    for (int bn = 0; bn < 2; bn++)
#pragma unroll
      for (int kh = 0; kh < 2; kh++) bHi[bn][kh] = RDB(buf, 2 + bn, kh);
    __builtin_amdgcn_s_setprio(1);
    QMFMA(0, 2, aF, bHi)
    __builtin_amdgcn_s_setprio(0);
    GBAR();
    // ---- P3
#pragma unroll
    for (int am = 0; am < 4; am++)
#pragma unroll
      for (int kh = 0; kh < 2; kh++) aF[am][kh] = RDA(buf, 4 + am, kh);
    if (pf) stageB(buf, kof2);
    __builtin_amdgcn_s_setprio(1);
    QMFMA(4, 2, aF, bHi)
    __builtin_amdgcn_s_setprio(0);
    GBAR();
    // ---- P4
    if (pf) stageA(buf, kof2);
    __builtin_amdgcn_s_setprio(1);
    QMFMA(4, 0, aF, bLo)
    __builtin_amdgcn_s_setprio(0);
    if (t + 1 < NT) {
      if (pf) asm volatile("s_waitcnt vmcnt(8)" ::: "memory");
      else    asm volatile("s_waitcnt vmcnt(0)" ::: "memory");
      __builtin_amdgcn_s_barrier();
      asm volatile("" ::: "memory");
    }
  }
#undef RDA
#undef RDB
#undef QMFMA

  // epilogue
#pragma unroll
  for (int am = 0; am < 8; am++)
#pragma unroll
    for (int bn = 0; bn < 4; bn++) {
      int rowi = m0 + wm + am * 16 + quad * 4;
      int col = n0 + wn + bn * 16 + l15;
      float bcol = GELU ? bias[col] : 0.0f;
#pragma unroll
      for (int r = 0; r < 4; r++) {
        float val = acc[am][bn][r] + bcol;
        if (GELU) val = gelu_tanh(val);
        outz[(size_t)(rowi + r) * Nn + col] = f2bf(val);
      }
    }
}

extern "C" void kernel_launch(void* const* d_in, const int* in_sizes, int n_in,
                              void* d_out, int out_size, void* d_ws, size_t ws_size,
                              hipStream_t stream) {
  const float* q = (const float*)d_in[0];
  const float* k = (const float*)d_in[1];
  const float* v = (const float*)d_in[2];
  const float* fc1_w = (const float*)d_in[3];
  const float* fc1_b = (const float*)d_in[4];
  const float* fc2_w = (const float*)d_in[5];
  const float* fc2_b = (const float*)d_in[6];
  const float* ln1_w = (const float*)d_in[7];
  const float* ln1_b = (const float*)d_in[8];
  const float* ln2_w = (const float*)d_in[9];
  const float* ln2_b = (const float*)d_in[10];
  float* out = (float*)d_out;

  char* ws = (char*)d_ws;
  size_t off = 0;
  u16* kb = (u16*)(ws + off); off += (size_t)TT * CC * 2;         // 8 MB
  u16* vtb = (u16*)(ws + off); off += (size_t)TT * CC * 2;        // 8 MB
  u16* w1b = (u16*)(ws + off); off += (size_t)HIDE_ * CC * 2;     // 2 MB
  u16* w2b = (u16*)(ws + off); off += (size_t)CC * HIDE_ * 2;     // 2 MB
  u16* ou = (u16*)(ws + off); off += (size_t)2 * TT * CC * 2;     // 16 MB
  float* lsum = (float*)(ws + off); off += (size_t)2 * TT * HH * 4;  // 512 KB
  u16* q2b = (u16*)(ws + off); off += (size_t)TT * CC * 2;        // 8 MB
  u16* hbuf = (u16*)(ws + off); off += (size_t)TT * HIDE_ * 2;    // 32 MB
  u16* mp = (u16*)(ws + off); off += (size_t)4 * TT * CC * 2;     // 32 MB (split-K 4)

  const float QS = 0.18033688011112042f;   // (1/8) * log2(e)
  prep_kernel<<<4096, 256, 0, stream>>>(k, fc1_w, fc2_w, v, kb, w1b, w2b, vtb);
  attn_kernel<<<dim3(512, 2), 256, 0, stream>>>(q, kb, vtb, ou, lsum, QS);
  ln1_kernel<<<2048, 256, 0, stream>>>(q, ou, lsum, ln1_w, ln1_b, q2b);
  // fc1: M=8192, N=2048, K=512 -> 256 blocks (1/CU), gx=8, gy=32, NT=8
  gemm256<true><<<256, 512, 0, stream>>>(q2b, w1b, fc1_b, hbuf, HIDE_, CC, 8, 8, 32);
  // fc2: M=8192, N=512, K=2048 split-K 4 -> 256 blocks, gx=2, gy=32, NT=8
  gemm256<false><<<256, 512, 0, stream>>>(hbuf, w2b, fc2_b, mp, CC, HIDE_, 8, 2, 32);
  ln2_kernel<<<2048, 256, 0, stream>>>(q2b, mp, fc2_b, ln2_w, ln2_b, out);
}

// Round 7
// 222.279 us; speedup vs baseline: 1.1762x; 1.1762x over previous
//
#include <hip/hip_runtime.h>
#include <math.h>

typedef unsigned short u16;
typedef __bf16 bf16_t;
typedef bf16_t bf16x4 __attribute__((ext_vector_type(4)));
typedef bf16_t bf16x8 __attribute__((ext_vector_type(8)));
typedef short s16x4 __attribute__((ext_vector_type(4)));
typedef float f32x4 __attribute__((ext_vector_type(4)));

typedef const __attribute__((address_space(1))) void* gcp;
typedef __attribute__((address_space(3))) void* lcp;

#define BB 4
#define NN 2048
#define CC 512
#define HH 8
#define HD 64
#define HIDE_ 2048
#define TT (BB*NN)  // 8192

#if __has_builtin(__builtin_amdgcn_exp2f)
#define EXP2(x) __builtin_amdgcn_exp2f(x)
#else
#define EXP2(x) __expf((x) * 0.69314718055994531f)
#endif

#if __has_builtin(__builtin_amdgcn_rcpf)
#define RCP(x) __builtin_amdgcn_rcpf(x)
#else
#define RCP(x) (1.0f / (x))
#endif

__device__ __forceinline__ u16 f2bf(float f) {
  unsigned u = __float_as_uint(f);
  u += 0x7FFF + ((u >> 16) & 1);   // RNE
  return (u16)(u >> 16);
}

// bijective XCD-aware block swizzle (requires nwg % 8 == 0)
__device__ __forceinline__ int xcd_swz(int orig, int nwg) {
  return (orig & 7) * (nwg >> 3) + (orig >> 3);
}

__device__ __forceinline__ void bf8_to_f(const u16* p, float* f) {
  uint4 u = *(const uint4*)p;
  f[0] = __uint_as_float(u.x << 16); f[1] = __uint_as_float(u.x & 0xffff0000u);
  f[2] = __uint_as_float(u.y << 16); f[3] = __uint_as_float(u.y & 0xffff0000u);
  f[4] = __uint_as_float(u.z << 16); f[5] = __uint_as_float(u.z & 0xffff0000u);
  f[6] = __uint_as_float(u.w << 16); f[7] = __uint_as_float(u.w & 0xffff0000u);
}

// load 8 fp32, scale, pack to bf16x8
__device__ __forceinline__ bf16x8 ldq8(const float* p, float s) {
  float4 a = *(const float4*)p;
  float4 b = *(const float4*)(p + 4);
  bf16x8 r = {(bf16_t)(a.x * s), (bf16_t)(a.y * s), (bf16_t)(a.z * s), (bf16_t)(a.w * s),
              (bf16_t)(b.x * s), (bf16_t)(b.y * s), (bf16_t)(b.z * s), (bf16_t)(b.w * s)};
  return r;
}

// tanh-form GELU
__device__ __forceinline__ float gelu_tanh(float x) {
  float y = 0.7978845608028654f * x * (1.0f + 0.044715f * x * x);
  float a = y * 2.8853900817779268f;
  a = fminf(fmaxf(a, -30.0f), 30.0f);
  float e = EXP2(a);
  float t = (e - 1.0f) * RCP(e + 1.0f);
  return 0.5f * x * (1.0f + t);
}

// ---------------- prep: k/fc1_w/fc2_w cvt + V^T transpose ----------------
__global__ __launch_bounds__(256) void prep_kernel(const float* __restrict__ k,
                                                   const float* __restrict__ fc1w,
                                                   const float* __restrict__ fc2w,
                                                   const float* __restrict__ v,
                                                   u16* __restrict__ kb,
                                                   u16* __restrict__ w1b,
                                                   u16* __restrict__ w2b,
                                                   u16* __restrict__ vtb) {
  __shared__ __align__(16) u16 T[64 * 72];
  int bid = blockIdx.x, tid = threadIdx.x;
  if (bid < 3072) {
    const float* in;
    u16* out;
    int rel;
    if (bid < 2048)      { in = k;    out = kb;  rel = bid; }
    else if (bid < 2560) { in = fc1w; out = w1b; rel = bid - 2048; }
    else                 { in = fc2w; out = w2b; rel = bid - 2560; }
    int i = (rel * 256 + tid) * 8;
    float4 a = *(const float4*)(in + i);
    float4 b2 = *(const float4*)(in + i + 4);
    u16 r[8] = {f2bf(a.x), f2bf(a.y), f2bf(a.z), f2bf(a.w),
                f2bf(b2.x), f2bf(b2.y), f2bf(b2.z), f2bf(b2.w)};
    *(uint4*)(out + i) = *(const uint4*)r;
    return;
  }
  int tv = bid - 3072;
  int j0 = (tv & 31) * 64;
  int bh = tv >> 5;
  int b = bh >> 3, h = bh & 7;
#pragma unroll
  for (int i = 0; i < 16; i++) {
    int idx = i * 256 + tid;
    int j = idx >> 6, d = idx & 63;
    T[d * 72 + j] = f2bf(v[((size_t)(b * NN + j0 + j)) * CC + h * 64 + d]);
  }
  __syncthreads();
#pragma unroll
  for (int i = 0; i < 16; i++) {
    int idx = i * 256 + tid;
    int d = idx >> 6, j = idx & 63;
    vtb[((size_t)(bh * 64 + d)) * NN + j0 + j] = T[d * 72 + j];
  }
}

// ---------------- flash attention: dual-Q-group (32 q/wave), split-K halves ----------------
// round-5 exact (best measured 54us): KVBLK=64, single-buffer, setprio, XCD swizzle.
__global__ __launch_bounds__(256, 4) void attn_kernel(const float* __restrict__ qf,
                                                      const u16* __restrict__ kb,
                                                      const u16* __restrict__ vtb,
                                                      u16* __restrict__ ou,
                                                      float* __restrict__ lsum,
                                                      float qs) {
  __shared__ __align__(16) u16 Ks[64 * 64];
  __shared__ __align__(16) u16 Vs[64 * 64];
  int tid = threadIdx.x, wave = tid >> 6, lane = tid & 63;
  int l15 = lane & 15, quad = lane >> 4;
  int r7 = l15 & 7;
  int bid = xcd_swz(blockIdx.x, 512);
  int half = blockIdx.y;
  int qt = bid & 15, h = (bid >> 4) & 7, b = bid >> 7;
  int qw = qt * 128 + wave * 32;
  int j0base = half * 1024;

  u16* ou_ = ou + (size_t)half * TT * CC;
  float* ls_ = lsum + (size_t)half * TT * HH;

  const float* qp = qf + ((size_t)(b * NN + qw + l15)) * CC + h * 64 + quad * 8;
  bf16x8 qfA0 = ldq8(qp, qs);
  bf16x8 qfA1 = ldq8(qp + 32, qs);
  bf16x8 qfB0 = ldq8(qp + (size_t)16 * CC, qs);
  bf16x8 qfB1 = ldq8(qp + (size_t)16 * CC + 32, qs);

  int rl = lane >> 3;
  int cb = (lane & 7) ^ rl;
  int rK = wave * 16 + rl;
  size_t vtbase = ((size_t)(b * HH + h)) * 64 * NN;
  const u16* kp0 = kb + ((size_t)(b * NN + j0base + rK)) * CC + h * 64 + cb * 8;
  const u16* kp1 = kp0 + (size_t)8 * CC;
  const u16* vp0 = vtb + vtbase + (size_t)rK * NN + j0base + cb * 8;
  const u16* vp1 = vp0 + (size_t)8 * NN;
  lcp lK0 = (lcp)&Ks[wave * 16 * 64];
  lcp lK1 = (lcp)&Ks[wave * 16 * 64 + 8 * 64];
  lcp lV0 = (lcp)&Vs[wave * 16 * 64];
  lcp lV1 = (lcp)&Vs[wave * 16 * 64 + 8 * 64];

  float lA = 0.f, lB = 0.f;
  f32x4 oA[4] = {}, oB[4] = {};

  for (int kt = 0; kt < 16; kt++) {
    __syncthreads();
    __builtin_amdgcn_global_load_lds((gcp)kp0, lK0, 16, 0, 0);
    __builtin_amdgcn_global_load_lds((gcp)kp1, lK1, 16, 0, 0);
    __builtin_amdgcn_global_load_lds((gcp)vp0, lV0, 16, 0, 0);
    __builtin_amdgcn_global_load_lds((gcp)vp1, lV1, 16, 0, 0);
    kp0 += (size_t)64 * CC; kp1 += (size_t)64 * CC;
    vp0 += 64; vp1 += 64;
    __syncthreads();

    s16x4 pfA[4], pfB[4];
    __builtin_amdgcn_s_setprio(1);
#pragma unroll
    for (int nt = 0; nt < 4; nt++) {
      const u16* krow = &Ks[(nt * 16 + l15) * 64];
      bf16x8 k0 = *(const bf16x8*)&krow[(quad ^ r7) * 8];
      bf16x8 k1 = *(const bf16x8*)&krow[((quad + 4) ^ r7) * 8];
      f32x4 zA = {0.f, 0.f, 0.f, 0.f}, zB = {0.f, 0.f, 0.f, 0.f};
      zA = __builtin_amdgcn_mfma_f32_16x16x32_bf16(k0, qfA0, zA, 0, 0, 0);
      zA = __builtin_amdgcn_mfma_f32_16x16x32_bf16(k1, qfA1, zA, 0, 0, 0);
      zB = __builtin_amdgcn_mfma_f32_16x16x32_bf16(k0, qfB0, zB, 0, 0, 0);
      zB = __builtin_amdgcn_mfma_f32_16x16x32_bf16(k1, qfB1, zB, 0, 0, 0);
      float a0 = EXP2(zA[0]), a1 = EXP2(zA[1]), a2 = EXP2(zA[2]), a3 = EXP2(zA[3]);
      float b0 = EXP2(zB[0]), b1 = EXP2(zB[1]), b2 = EXP2(zB[2]), b3 = EXP2(zB[3]);
      lA += (a0 + a1) + (a2 + a3);
      lB += (b0 + b1) + (b2 + b3);
      bf16x4 ta = {(bf16_t)a0, (bf16_t)a1, (bf16_t)a2, (bf16_t)a3};
      bf16x4 tb = {(bf16_t)b0, (bf16_t)b1, (bf16_t)b2, (bf16_t)b3};
      pfA[nt] = __builtin_bit_cast(s16x4, ta);
      pfB[nt] = __builtin_bit_cast(s16x4, tb);
    }
#pragma unroll
    for (int dt = 0; dt < 4; dt++) {
      const u16* vrow = &Vs[(dt * 16 + l15) * 64];
#pragma unroll
      for (int nt = 0; nt < 4; nt++) {
        s16x4 vf = *(const s16x4*)
            &vrow[((nt * 2 + (quad >> 1)) ^ r7) * 8 + (quad & 1) * 4];
        oA[dt] = __builtin_amdgcn_mfma_f32_16x16x16bf16_1k(vf, pfA[nt], oA[dt], 0, 0, 0);
        oB[dt] = __builtin_amdgcn_mfma_f32_16x16x16bf16_1k(vf, pfB[nt], oB[dt], 0, 0, 0);
      }
    }
    __builtin_amdgcn_s_setprio(0);
  }

  lA += __shfl_xor(lA, 16, 64);
  lA += __shfl_xor(lA, 32, 64);
  lB += __shfl_xor(lB, 16, 64);
  lB += __shfl_xor(lB, 32, 64);
  if (quad == 0) {
    ls_[(size_t)(b * NN + qw + l15) * HH + h] = lA;
    ls_[(size_t)(b * NN + qw + 16 + l15) * HH + h] = lB;
  }
  size_t obase = ((size_t)(b * NN + qw + l15)) * CC + h * 64 + quad * 4;
#pragma unroll
  for (int dt = 0; dt < 4; dt++) {
    u16 ra[4] = {f2bf(oA[dt][0]), f2bf(oA[dt][1]), f2bf(oA[dt][2]), f2bf(oA[dt][3])};
    u16 rb[4] = {f2bf(oB[dt][0]), f2bf(oB[dt][1]), f2bf(oB[dt][2]), f2bf(oB[dt][3])};
    *(uint2*)&ou_[obase + dt * 16] = *(const uint2*)ra;
    *(uint2*)&ou_[obase + (size_t)16 * CC + dt * 16] = *(const uint2*)rb;
  }
}

// ---------------- ln1: combine bf16 O_u halves + fp32 q residual + LN -> bf16 ----------------
__global__ __launch_bounds__(256) void ln1_kernel(const float* __restrict__ q,
                                                  const u16* __restrict__ ou,
                                                  const float* __restrict__ lsum,
                                                  const float* __restrict__ w,
                                                  const float* __restrict__ bb,
                                                  u16* __restrict__ outb) {
  int tid = threadIdx.x;
  int row = blockIdx.x * 4 + (tid >> 6);
  int lane = tid & 63;
  int h = lane >> 3;
  size_t base = (size_t)row * CC + lane * 8;
  const u16* ou1 = ou + (size_t)TT * CC;
  const float* ls1 = lsum + (size_t)TT * HH;
  float li = lsum[(size_t)row * HH + h] + ls1[(size_t)row * HH + h];
  float inv = 1.0f / li;
  float4 a0 = *(const float4*)(q + base);
  float4 a1 = *(const float4*)(q + base + 4);
  float c[8], d[8];
  bf8_to_f(ou + base, c);
  bf8_to_f(ou1 + base, d);
  float av[8] = {a0.x, a0.y, a0.z, a0.w, a1.x, a1.y, a1.z, a1.w};
  float x[8];
#pragma unroll
  for (int i = 0; i < 8; i++) x[i] = av[i] + (c[i] + d[i]) * inv;
  float sum = 0.f, sq = 0.f;
#pragma unroll
  for (int i = 0; i < 8; i++) { sum += x[i]; sq += x[i] * x[i]; }
#pragma unroll
  for (int msk = 1; msk < 64; msk <<= 1) {
    sum += __shfl_xor(sum, msk, 64);
    sq += __shfl_xor(sq, msk, 64);
  }
  float mu = sum * (1.0f / CC);
  float var = sq * (1.0f / CC) - mu * mu;
  float rs = rsqrtf(var + 1e-6f);
  int col = lane * 8;
  float4 w0 = *(const float4*)(w + col);
  float4 w1 = *(const float4*)(w + col + 4);
  float4 b0 = *(const float4*)(bb + col);
  float4 b1 = *(const float4*)(bb + col + 4);
  float wv[8] = {w0.x, w0.y, w0.z, w0.w, w1.x, w1.y, w1.z, w1.w};
  float bv[8] = {b0.x, b0.y, b0.z, b0.w, b1.x, b1.y, b1.z, b1.w};
  u16 r[8];
#pragma unroll
  for (int i = 0; i < 8; i++) r[i] = f2bf((x[i] - mu) * rs * wv[i] + bv[i]);
  *(uint4*)(outb + base) = *(const uint4*)r;
}

// ---------------- ln2: bf16 residual + bf16 split-K partials (x4) + bias + LN ----------------
__global__ __launch_bounds__(256) void ln2_kernel(const u16* __restrict__ q2b,
                                                  const u16* __restrict__ mp,
                                                  const float* __restrict__ fb,
                                                  const float* __restrict__ w,
                                                  const float* __restrict__ bb,
                                                  float* __restrict__ outf) {
  int tid = threadIdx.x;
  int row = blockIdx.x * 4 + (tid >> 6);
  int lane = tid & 63;
  size_t base = (size_t)row * CC + lane * 8;
  const u16* mp1 = mp + (size_t)TT * CC;
  const u16* mp2 = mp + (size_t)2 * TT * CC;
  const u16* mp3 = mp + (size_t)3 * TT * CC;
  int col = lane * 8;
  float a[8], c[8], d[8], e[8], g[8];
  bf8_to_f(q2b + base, a);
  bf8_to_f(mp + base, c);
  bf8_to_f(mp1 + base, d);
  bf8_to_f(mp2 + base, e);
  bf8_to_f(mp3 + base, g);
  float4 f0 = *(const float4*)(fb + col);
  float4 f1 = *(const float4*)(fb + col + 4);
  float fbv[8] = {f0.x, f0.y, f0.z, f0.w, f1.x, f1.y, f1.z, f1.w};
  float x[8];
#pragma unroll
  for (int i = 0; i < 8; i++) x[i] = a[i] + ((c[i] + d[i]) + (e[i] + g[i])) + fbv[i];
  float sum = 0.f, sq = 0.f;
#pragma unroll
  for (int i = 0; i < 8; i++) { sum += x[i]; sq += x[i] * x[i]; }
#pragma unroll
  for (int msk = 1; msk < 64; msk <<= 1) {
    sum += __shfl_xor(sum, msk, 64);
    sq += __shfl_xor(sq, msk, 64);
  }
  float mu = sum * (1.0f / CC);
  float var = sq * (1.0f / CC) - mu * mu;
  float rs = rsqrtf(var + 1e-6f);
  float4 w0 = *(const float4*)(w + col);
  float4 w1 = *(const float4*)(w + col + 4);
  float4 b0 = *(const float4*)(bb + col);
  float4 b1 = *(const float4*)(bb + col + 4);
  float wv[8] = {w0.x, w0.y, w0.z, w0.w, w1.x, w1.y, w1.z, w1.w};
  float bv[8] = {b0.x, b0.y, b0.z, b0.w, b1.x, b1.y, b1.z, b1.w};
  float y[8];
#pragma unroll
  for (int i = 0; i < 8; i++) y[i] = (x[i] - mu) * rs * wv[i] + bv[i];
  *(float4*)(outf + base) = make_float4(y[0], y[1], y[2], y[3]);
  *(float4*)(outf + base + 4) = make_float4(y[4], y[5], y[6], y[7]);
}

// ---------------- GEMM 128x128 tile, BK=64, 4 waves, dbuf + counted-vmcnt, 2 blocks/CU ----------
// C = A*B^T. Per K-tile: {read all 16 frags ; MFMA n-lo ; lgkmcnt(0)+barrier ;
// prefetch t+2 into cur buf (provably dead) ; MFMA n-hi (register-only, hides issue) ;
// vmcnt(8) ; barrier}. 64 KB LDS -> 2 resident blocks/CU cover each other's stalls.
template <bool GELU>
__global__ __launch_bounds__(256) void gemm128(const u16* __restrict__ A,
                                               const u16* __restrict__ Bw,
                                               const float* __restrict__ bias,
                                               u16* __restrict__ outb,
                                               int Nn, int K, int NT,
                                               int gx, int gy) {
  __shared__ __align__(16) u16 As[2][128 * 64];
  __shared__ __align__(16) u16 Bs[2][128 * 64];
  int tid = threadIdx.x, wave = tid >> 6, lane = tid & 63;
  int l15 = lane & 15, quad = lane >> 4;
  int r7 = l15 & 7;
  int l = xcd_swz(blockIdx.x, gridDim.x);
  int bx = l % gx;
  int by = (l / gx) % gy;
  int bz = l / (gx * gy);
  int m0 = by * 128, n0 = bx * 128;
  int kbeg = bz * (NT * 64);
  u16* outz = outb + (size_t)bz * ((size_t)TT * CC);
  int wm = (wave >> 1) * 64, wn = (wave & 1) * 64;
  int w32 = wave * 32;
  int rl = lane >> 3;
  int cb = (lane & 7) ^ rl;
  const u16* Ap = &A[(size_t)(m0 + w32 + rl) * K + kbeg + cb * 8];
  const u16* Bp = &Bw[(size_t)(n0 + w32 + rl) * K + kbeg + cb * 8];
  unsigned sb = w32 * 64;   // wave's staging slice (u16 elems)

  f32x4 acc[4][4] = {};

  auto stage = [&](int buf, int kofs) {
#pragma unroll
    for (int c = 0; c < 4; c++) {
      __builtin_amdgcn_global_load_lds((gcp)(Ap + kofs + (size_t)(c * 8) * K),
          (lcp)&As[buf][sb + c * 512], 16, 0, 0);
      __builtin_amdgcn_global_load_lds((gcp)(Bp + kofs + (size_t)(c * 8) * K),
          (lcp)&Bs[buf][sb + c * 512], 16, 0, 0);
    }
  };

  // prologue: 2-deep prefetch
  stage(0, 0);
  stage(1, 64);
  asm volatile("s_waitcnt vmcnt(8)" ::: "memory");   // tile 0 complete
  __builtin_amdgcn_s_barrier();

  for (int t = 0; t < NT; t++) {
    int buf = t & 1;
    bool pf = (t + 2) < NT;
    bf16x8 aF[4][2], bF[4][2];
#pragma unroll
    for (int m = 0; m < 4; m++)
#pragma unroll
      for (int kh = 0; kh < 2; kh++)
        aF[m][kh] = *(const bf16x8*)&As[buf][(wm + m * 16 + l15) * 64 +
                                            ((kh * 4 + quad) ^ r7) * 8];
#pragma unroll
    for (int n = 0; n < 4; n++)
#pragma unroll
      for (int kh = 0; kh < 2; kh++)
        bF[n][kh] = *(const bf16x8*)&Bs[buf][(wn + n * 16 + l15) * 64 +
                                            ((kh * 4 + quad) ^ r7) * 8];
    __builtin_amdgcn_s_setprio(1);
#pragma unroll
    for (int m = 0; m < 4; m++)
#pragma unroll
      for (int n = 0; n < 2; n++)
#pragma unroll
        for (int kh = 0; kh < 2; kh++)
          acc[m][n] = __builtin_amdgcn_mfma_f32_16x16x32_bf16(aF[m][kh], bF[n][kh],
                                                              acc[m][n], 0, 0, 0);
    __builtin_amdgcn_s_setprio(0);
    // all LDS reads of buf complete (lgkmcnt 0) in every wave before anyone overwrites
    asm volatile("s_waitcnt lgkmcnt(0)\n\ts_barrier" ::: "memory");
    if (pf) stage(buf, (t + 2) * 64);   // overwrite cur buf: dead (all frags in regs)
    __builtin_amdgcn_s_setprio(1);
#pragma unroll
    for (int m = 0; m < 4; m++)
#pragma unroll
      for (int n = 2; n < 4; n++)
#pragma unroll
        for (int kh = 0; kh < 2; kh++)
          acc[m][n] = __builtin_amdgcn_mfma_f32_16x16x32_bf16(aF[m][kh], bF[n][kh],
                                                              acc[m][n], 0, 0, 0);
    __builtin_amdgcn_s_setprio(0);
    if (t + 1 < NT) {
      if (pf) asm volatile("s_waitcnt vmcnt(8)" ::: "memory");  // t+1's 8 loads done
      else    asm volatile("s_waitcnt vmcnt(0)" ::: "memory");
      __builtin_amdgcn_s_barrier();
      asm volatile("" ::: "memory");
    }
  }

  // epilogue
#pragma unroll
  for (int am = 0; am < 4; am++)
#pragma unroll
    for (int bn = 0; bn < 4; bn++) {
      int rowi = m0 + wm + am * 16 + quad * 4;
      int col = n0 + wn + bn * 16 + l15;
      float bcol = GELU ? bias[col] : 0.0f;
#pragma unroll
      for (int r = 0; r < 4; r++) {
        float val = acc[am][bn][r] + bcol;
        if (GELU) val = gelu_tanh(val);
        outz[(size_t)(rowi + r) * Nn + col] = f2bf(val);
      }
    }
}

extern "C" void kernel_launch(void* const* d_in, const int* in_sizes, int n_in,
                              void* d_out, int out_size, void* d_ws, size_t ws_size,
                              hipStream_t stream) {
  const float* q = (const float*)d_in[0];
  const float* k = (const float*)d_in[1];
  const float* v = (const float*)d_in[2];
  const float* fc1_w = (const float*)d_in[3];
  const float* fc1_b = (const float*)d_in[4];
  const float* fc2_w = (const float*)d_in[5];
  const float* fc2_b = (const float*)d_in[6];
  const float* ln1_w = (const float*)d_in[7];
  const float* ln1_b = (const float*)d_in[8];
  const float* ln2_w = (const float*)d_in[9];
  const float* ln2_b = (const float*)d_in[10];
  float* out = (float*)d_out;

  char* ws = (char*)d_ws;
  size_t off = 0;
  u16* kb = (u16*)(ws + off); off += (size_t)TT * CC * 2;         // 8 MB
  u16* vtb = (u16*)(ws + off); off += (size_t)TT * CC * 2;        // 8 MB
  u16* w1b = (u16*)(ws + off); off += (size_t)HIDE_ * CC * 2;     // 2 MB
  u16* w2b = (u16*)(ws + off); off += (size_t)CC * HIDE_ * 2;     // 2 MB
  u16* ou = (u16*)(ws + off); off += (size_t)2 * TT * CC * 2;     // 16 MB
  float* lsum = (float*)(ws + off); off += (size_t)2 * TT * HH * 4;  // 512 KB
  u16* q2b = (u16*)(ws + off); off += (size_t)TT * CC * 2;        // 8 MB
  u16* hbuf = (u16*)(ws + off); off += (size_t)TT * HIDE_ * 2;    // 32 MB
  u16* mp = (u16*)(ws + off); off += (size_t)4 * TT * CC * 2;     // 32 MB (split-K 4)

  const float QS = 0.18033688011112042f;   // (1/8) * log2(e)
  prep_kernel<<<4096, 256, 0, stream>>>(k, fc1_w, fc2_w, v, kb, w1b, w2b, vtb);
  attn_kernel<<<dim3(512, 2), 256, 0, stream>>>(q, kb, vtb, ou, lsum, QS);
  ln1_kernel<<<2048, 256, 0, stream>>>(q, ou, lsum, ln1_w, ln1_b, q2b);
  // fc1: M=8192, N=2048, K=512 -> 1024 blocks (gx=16, gy=64), NT=8
  gemm128<true><<<1024, 256, 0, stream>>>(q2b, w1b, fc1_b, hbuf, HIDE_, CC, 8, 16, 64);
  // fc2: M=8192, N=512, K=2048 split-K 4 -> 1024 blocks (gx=4, gy=64, z=4), NT=8
  gemm128<false><<<1024, 256, 0, stream>>>(hbuf, w2b, fc2_b, mp, CC, HIDE_, 8, 4, 64);
  ln2_kernel<<<2048, 256, 0, stream>>>(q2b, mp, fc2_b, ln2_w, ln2_b, out);
}

// Round 8
// 216.069 us; speedup vs baseline: 1.2100x; 1.0287x over previous
//
#include <hip/hip_runtime.h>
#include <math.h>

typedef unsigned short u16;
typedef __bf16 bf16_t;
typedef bf16_t bf16x4 __attribute__((ext_vector_type(4)));
typedef bf16_t bf16x8 __attribute__((ext_vector_type(8)));
typedef short s16x4 __attribute__((ext_vector_type(4)));
typedef float f32x4 __attribute__((ext_vector_type(4)));

typedef const __attribute__((address_space(1))) void* gcp;
typedef __attribute__((address_space(3))) void* lcp;

#define BB 4
#define NN 2048
#define CC 512
#define HH 8
#define HD 64
#define HIDE_ 2048
#define TT (BB*NN)  // 8192

#if __has_builtin(__builtin_amdgcn_exp2f)
#define EXP2(x) __builtin_amdgcn_exp2f(x)
#else
#define EXP2(x) __expf((x) * 0.69314718055994531f)
#endif

#if __has_builtin(__builtin_amdgcn_rcpf)
#define RCP(x) __builtin_amdgcn_rcpf(x)
#else
#define RCP(x) (1.0f / (x))
#endif

__device__ __forceinline__ u16 f2bf(float f) {
  unsigned u = __float_as_uint(f);
  u += 0x7FFF + ((u >> 16) & 1);   // RNE
  return (u16)(u >> 16);
}

// bijective XCD-aware block swizzle (requires nwg % 8 == 0)
__device__ __forceinline__ int xcd_swz(int orig, int nwg) {
  return (orig & 7) * (nwg >> 3) + (orig >> 3);
}

__device__ __forceinline__ void bf8_to_f(const u16* p, float* f) {
  uint4 u = *(const uint4*)p;
  f[0] = __uint_as_float(u.x << 16); f[1] = __uint_as_float(u.x & 0xffff0000u);
  f[2] = __uint_as_float(u.y << 16); f[3] = __uint_as_float(u.y & 0xffff0000u);
  f[4] = __uint_as_float(u.z << 16); f[5] = __uint_as_float(u.z & 0xffff0000u);
  f[6] = __uint_as_float(u.w << 16); f[7] = __uint_as_float(u.w & 0xffff0000u);
}

// load 8 fp32, scale, pack to bf16x8
__device__ __forceinline__ bf16x8 ldq8(const float* p, float s) {
  float4 a = *(const float4*)p;
  float4 b = *(const float4*)(p + 4);
  bf16x8 r = {(bf16_t)(a.x * s), (bf16_t)(a.y * s), (bf16_t)(a.z * s), (bf16_t)(a.w * s),
              (bf16_t)(b.x * s), (bf16_t)(b.y * s), (bf16_t)(b.z * s), (bf16_t)(b.w * s)};
  return r;
}

// tanh-form GELU
__device__ __forceinline__ float gelu_tanh(float x) {
  float y = 0.7978845608028654f * x * (1.0f + 0.044715f * x * x);
  float a = y * 2.8853900817779268f;
  a = fminf(fmaxf(a, -30.0f), 30.0f);
  float e = EXP2(a);
  float t = (e - 1.0f) * RCP(e + 1.0f);
  return 0.5f * x * (1.0f + t);
}

// ---------------- prep: k/fc1_w/fc2_w cvt + V^T transpose (vectorized) ----------------
__global__ __launch_bounds__(256) void prep_kernel(const float* __restrict__ k,
                                                   const float* __restrict__ fc1w,
                                                   const float* __restrict__ fc2w,
                                                   const float* __restrict__ v,
                                                   u16* __restrict__ kb,
                                                   u16* __restrict__ w1b,
                                                   u16* __restrict__ w2b,
                                                   u16* __restrict__ vtb) {
  __shared__ __align__(16) u16 T[64 * 72];
  int bid = blockIdx.x, tid = threadIdx.x;
  if (bid < 3072) {
    const float* in;
    u16* out;
    int rel;
    if (bid < 2048)      { in = k;    out = kb;  rel = bid; }
    else if (bid < 2560) { in = fc1w; out = w1b; rel = bid - 2048; }
    else                 { in = fc2w; out = w2b; rel = bid - 2560; }
    int i = (rel * 256 + tid) * 8;
    float4 a = *(const float4*)(in + i);
    float4 b2 = *(const float4*)(in + i + 4);
    u16 r[8] = {f2bf(a.x), f2bf(a.y), f2bf(a.z), f2bf(a.w),
                f2bf(b2.x), f2bf(b2.y), f2bf(b2.z), f2bf(b2.w)};
    *(uint4*)(out + i) = *(const uint4*)r;
    return;
  }
  int tv = bid - 3072;
  int j0 = (tv & 31) * 64;
  int bh = tv >> 5;
  int b = bh >> 3, h = bh & 7;
  // fill: float4 reads along d, transposed scalar LDS writes
#pragma unroll
  for (int i = 0; i < 4; i++) {
    int idx = i * 256 + tid;
    int j = idx >> 4, dq = idx & 15;
    float4 a = *(const float4*)(v + ((size_t)(b * NN + j0 + j)) * CC + h * 64 + dq * 4);
    T[(dq * 4 + 0) * 72 + j] = f2bf(a.x);
    T[(dq * 4 + 1) * 72 + j] = f2bf(a.y);
    T[(dq * 4 + 2) * 72 + j] = f2bf(a.z);
    T[(dq * 4 + 3) * 72 + j] = f2bf(a.w);
  }
  __syncthreads();
  // drain: uint4 (8 u16) per thread, 128B-contiguous global segments
#pragma unroll
  for (int i = 0; i < 2; i++) {
    int idx = i * 256 + tid;
    int d = idx >> 3, jb = idx & 7;
    uint4 val = *(const uint4*)&T[d * 72 + jb * 8];
    *(uint4*)&vtb[((size_t)(bh * 64 + d)) * NN + j0 + jb * 8] = val;
  }
}

// ---------------- flash attention: dual-Q-group (32 q/wave), split-K halves ----------------
// round-5 exact (best measured 54us): KVBLK=64, single-buffer, setprio, XCD swizzle.
__global__ __launch_bounds__(256, 4) void attn_kernel(const float* __restrict__ qf,
                                                      const u16* __restrict__ kb,
                                                      const u16* __restrict__ vtb,
                                                      u16* __restrict__ ou,
                                                      float* __restrict__ lsum,
                                                      float qs) {
  __shared__ __align__(16) u16 Ks[64 * 64];
  __shared__ __align__(16) u16 Vs[64 * 64];
  int tid = threadIdx.x, wave = tid >> 6, lane = tid & 63;
  int l15 = lane & 15, quad = lane >> 4;
  int r7 = l15 & 7;
  int bid = xcd_swz(blockIdx.x, 512);
  int half = blockIdx.y;
  int qt = bid & 15, h = (bid >> 4) & 7, b = bid >> 7;
  int qw = qt * 128 + wave * 32;
  int j0base = half * 1024;

  u16* ou_ = ou + (size_t)half * TT * CC;
  float* ls_ = lsum + (size_t)half * TT * HH;

  const float* qp = qf + ((size_t)(b * NN + qw + l15)) * CC + h * 64 + quad * 8;
  bf16x8 qfA0 = ldq8(qp, qs);
  bf16x8 qfA1 = ldq8(qp + 32, qs);
  bf16x8 qfB0 = ldq8(qp + (size_t)16 * CC, qs);
  bf16x8 qfB1 = ldq8(qp + (size_t)16 * CC + 32, qs);

  int rl = lane >> 3;
  int cb = (lane & 7) ^ rl;
  int rK = wave * 16 + rl;
  size_t vtbase = ((size_t)(b * HH + h)) * 64 * NN;
  const u16* kp0 = kb + ((size_t)(b * NN + j0base + rK)) * CC + h * 64 + cb * 8;
  const u16* kp1 = kp0 + (size_t)8 * CC;
  const u16* vp0 = vtb + vtbase + (size_t)rK * NN + j0base + cb * 8;
  const u16* vp1 = vp0 + (size_t)8 * NN;
  lcp lK0 = (lcp)&Ks[wave * 16 * 64];
  lcp lK1 = (lcp)&Ks[wave * 16 * 64 + 8 * 64];
  lcp lV0 = (lcp)&Vs[wave * 16 * 64];
  lcp lV1 = (lcp)&Vs[wave * 16 * 64 + 8 * 64];

  float lA = 0.f, lB = 0.f;
  f32x4 oA[4] = {}, oB[4] = {};

  for (int kt = 0; kt < 16; kt++) {
    __syncthreads();
    __builtin_amdgcn_global_load_lds((gcp)kp0, lK0, 16, 0, 0);
    __builtin_amdgcn_global_load_lds((gcp)kp1, lK1, 16, 0, 0);
    __builtin_amdgcn_global_load_lds((gcp)vp0, lV0, 16, 0, 0);
    __builtin_amdgcn_global_load_lds((gcp)vp1, lV1, 16, 0, 0);
    kp0 += (size_t)64 * CC; kp1 += (size_t)64 * CC;
    vp0 += 64; vp1 += 64;
    __syncthreads();

    s16x4 pfA[4], pfB[4];
    __builtin_amdgcn_s_setprio(1);
#pragma unroll
    for (int nt = 0; nt < 4; nt++) {
      const u16* krow = &Ks[(nt * 16 + l15) * 64];
      bf16x8 k0 = *(const bf16x8*)&krow[(quad ^ r7) * 8];
      bf16x8 k1 = *(const bf16x8*)&krow[((quad + 4) ^ r7) * 8];
      f32x4 zA = {0.f, 0.f, 0.f, 0.f}, zB = {0.f, 0.f, 0.f, 0.f};
      zA = __builtin_amdgcn_mfma_f32_16x16x32_bf16(k0, qfA0, zA, 0, 0, 0);
      zA = __builtin_amdgcn_mfma_f32_16x16x32_bf16(k1, qfA1, zA, 0, 0, 0);
      zB = __builtin_amdgcn_mfma_f32_16x16x32_bf16(k0, qfB0, zB, 0, 0, 0);
      zB = __builtin_amdgcn_mfma_f32_16x16x32_bf16(k1, qfB1, zB, 0, 0, 0);
      float a0 = EXP2(zA[0]), a1 = EXP2(zA[1]), a2 = EXP2(zA[2]), a3 = EXP2(zA[3]);
      float b0 = EXP2(zB[0]), b1 = EXP2(zB[1]), b2 = EXP2(zB[2]), b3 = EXP2(zB[3]);
      lA += (a0 + a1) + (a2 + a3);
      lB += (b0 + b1) + (b2 + b3);
      bf16x4 ta = {(bf16_t)a0, (bf16_t)a1, (bf16_t)a2, (bf16_t)a3};
      bf16x4 tb = {(bf16_t)b0, (bf16_t)b1, (bf16_t)b2, (bf16_t)b3};
      pfA[nt] = __builtin_bit_cast(s16x4, ta);
      pfB[nt] = __builtin_bit_cast(s16x4, tb);
    }
#pragma unroll
    for (int dt = 0; dt < 4; dt++) {
      const u16* vrow = &Vs[(dt * 16 + l15) * 64];
#pragma unroll
      for (int nt = 0; nt < 4; nt++) {
        s16x4 vf = *(const s16x4*)
            &vrow[((nt * 2 + (quad >> 1)) ^ r7) * 8 + (quad & 1) * 4];
        oA[dt] = __builtin_amdgcn_mfma_f32_16x16x16bf16_1k(vf, pfA[nt], oA[dt], 0, 0, 0);
        oB[dt] = __builtin_amdgcn_mfma_f32_16x16x16bf16_1k(vf, pfB[nt], oB[dt], 0, 0, 0);
      }
    }
    __builtin_amdgcn_s_setprio(0);
  }

  lA += __shfl_xor(lA, 16, 64);
  lA += __shfl_xor(lA, 32, 64);
  lB += __shfl_xor(lB, 16, 64);
  lB += __shfl_xor(lB, 32, 64);
  if (quad == 0) {
    ls_[(size_t)(b * NN + qw + l15) * HH + h] = lA;
    ls_[(size_t)(b * NN + qw + 16 + l15) * HH + h] = lB;
  }
  size_t obase = ((size_t)(b * NN + qw + l15)) * CC + h * 64 + quad * 4;
#pragma unroll
  for (int dt = 0; dt < 4; dt++) {
    u16 ra[4] = {f2bf(oA[dt][0]), f2bf(oA[dt][1]), f2bf(oA[dt][2]), f2bf(oA[dt][3])};
    u16 rb[4] = {f2bf(oB[dt][0]), f2bf(oB[dt][1]), f2bf(oB[dt][2]), f2bf(oB[dt][3])};
    *(uint2*)&ou_[obase + dt * 16] = *(const uint2*)ra;
    *(uint2*)&ou_[obase + (size_t)16 * CC + dt * 16] = *(const uint2*)rb;
  }
}

// ---------------- ln1: combine bf16 O_u halves + fp32 q residual + LN -> bf16 ----------------
__global__ __launch_bounds__(256) void ln1_kernel(const float* __restrict__ q,
                                                  const u16* __restrict__ ou,
                                                  const float* __restrict__ lsum,
                                                  const float* __restrict__ w,
                                                  const float* __restrict__ bb,
                                                  u16* __restrict__ outb) {
  int tid = threadIdx.x;
  int row = blockIdx.x * 4 + (tid >> 6);
  int lane = tid & 63;
  int h = lane >> 3;
  size_t base = (size_t)row * CC + lane * 8;
  const u16* ou1 = ou + (size_t)TT * CC;
  const float* ls1 = lsum + (size_t)TT * HH;
  float li = lsum[(size_t)row * HH + h] + ls1[(size_t)row * HH + h];
  float inv = 1.0f / li;
  float4 a0 = *(const float4*)(q + base);
  float4 a1 = *(const float4*)(q + base + 4);
  float c[8], d[8];
  bf8_to_f(ou + base, c);
  bf8_to_f(ou1 + base, d);
  float av[8] = {a0.x, a0.y, a0.z, a0.w, a1.x, a1.y, a1.z, a1.w};
  float x[8];
#pragma unroll
  for (int i = 0; i < 8; i++) x[i] = av[i] + (c[i] + d[i]) * inv;
  float sum = 0.f, sq = 0.f;
#pragma unroll
  for (int i = 0; i < 8; i++) { sum += x[i]; sq += x[i] * x[i]; }
#pragma unroll
  for (int msk = 1; msk < 64; msk <<= 1) {
    sum += __shfl_xor(sum, msk, 64);
    sq += __shfl_xor(sq, msk, 64);
  }
  float mu = sum * (1.0f / CC);
  float var = sq * (1.0f / CC) - mu * mu;
  float rs = rsqrtf(var + 1e-6f);
  int col = lane * 8;
  float4 w0 = *(const float4*)(w + col);
  float4 w1 = *(const float4*)(w + col + 4);
  float4 b0 = *(const float4*)(bb + col);
  float4 b1 = *(const float4*)(bb + col + 4);
  float wv[8] = {w0.x, w0.y, w0.z, w0.w, w1.x, w1.y, w1.z, w1.w};
  float bv[8] = {b0.x, b0.y, b0.z, b0.w, b1.x, b1.y, b1.z, b1.w};
  u16 r[8];
#pragma unroll
  for (int i = 0; i < 8; i++) r[i] = f2bf((x[i] - mu) * rs * wv[i] + bv[i]);
  *(uint4*)(outb + base) = *(const uint4*)r;
}

// ---------------- ln2: bf16 residual + bf16 split-K partials (x2) + bias + LN ----------------
__global__ __launch_bounds__(256) void ln2_kernel(const u16* __restrict__ q2b,
                                                  const u16* __restrict__ mp,
                                                  const float* __restrict__ fb,
                                                  const float* __restrict__ w,
                                                  const float* __restrict__ bb,
                                                  float* __restrict__ outf) {
  int tid = threadIdx.x;
  int row = blockIdx.x * 4 + (tid >> 6);
  int lane = tid & 63;
  size_t base = (size_t)row * CC + lane * 8;
  const u16* mp1 = mp + (size_t)TT * CC;
  int col = lane * 8;
  float a[8], c[8], d[8];
  bf8_to_f(q2b + base, a);
  bf8_to_f(mp + base, c);
  bf8_to_f(mp1 + base, d);
  float4 f0 = *(const float4*)(fb + col);
  float4 f1 = *(const float4*)(fb + col + 4);
  float fbv[8] = {f0.x, f0.y, f0.z, f0.w, f1.x, f1.y, f1.z, f1.w};
  float x[8];
#pragma unroll
  for (int i = 0; i < 8; i++) x[i] = a[i] + (c[i] + d[i]) + fbv[i];
  float sum = 0.f, sq = 0.f;
#pragma unroll
  for (int i = 0; i < 8; i++) { sum += x[i]; sq += x[i] * x[i]; }
#pragma unroll
  for (int msk = 1; msk < 64; msk <<= 1) {
    sum += __shfl_xor(sum, msk, 64);
    sq += __shfl_xor(sq, msk, 64);
  }
  float mu = sum * (1.0f / CC);
  float var = sq * (1.0f / CC) - mu * mu;
  float rs = rsqrtf(var + 1e-6f);
  float4 w0 = *(const float4*)(w + col);
  float4 w1 = *(const float4*)(w + col + 4);
  float4 b0 = *(const float4*)(bb + col);
  float4 b1 = *(const float4*)(bb + col + 4);
  float wv[8] = {w0.x, w0.y, w0.z, w0.w, w1.x, w1.y, w1.z, w1.w};
  float bv[8] = {b0.x, b0.y, b0.z, b0.w, b1.x, b1.y, b1.z, b1.w};
  float y[8];
#pragma unroll
  for (int i = 0; i < 8; i++) y[i] = (x[i] - mu) * rs * wv[i] + bv[i];
  *(float4*)(outf + base) = make_float4(y[0], y[1], y[2], y[3]);
  *(float4*)(outf + base + 4) = make_float4(y[4], y[5], y[6], y[7]);
}

// ---------------- GEMM 128x128 tile, BK=64, 4 waves, dbuf + counted-vmcnt, 2 blocks/CU ----------
template <bool GELU>
__global__ __launch_bounds__(256) void gemm128(const u16* __restrict__ A,
                                               const u16* __restrict__ Bw,
                                               const float* __restrict__ bias,
                                               u16* __restrict__ outb,
                                               int Nn, int K, int NT,
                                               int gx, int gy) {
  __shared__ __align__(16) u16 As[2][128 * 64];
  __shared__ __align__(16) u16 Bs[2][128 * 64];
  int tid = threadIdx.x, wave = tid >> 6, lane = tid & 63;
  int l15 = lane & 15, quad = lane >> 4;
  int r7 = l15 & 7;
  int l = xcd_swz(blockIdx.x, gridDim.x);
  int bx = l % gx;
  int by = (l / gx) % gy;
  int bz = l / (gx * gy);
  int m0 = by * 128, n0 = bx * 128;
  int kbeg = bz * (NT * 64);
  u16* outz = outb + (size_t)bz * ((size_t)TT * CC);
  int wm = (wave >> 1) * 64, wn = (wave & 1) * 64;
  int w32 = wave * 32;
  int rl = lane >> 3;
  int cb = (lane & 7) ^ rl;
  const u16* Ap = &A[(size_t)(m0 + w32 + rl) * K + kbeg + cb * 8];
  const u16* Bp = &Bw[(size_t)(n0 + w32 + rl) * K + kbeg + cb * 8];
  unsigned sb = w32 * 64;   // wave's staging slice (u16 elems)

  f32x4 acc[4][4] = {};

  auto stage = [&](int buf, int kofs) {
#pragma unroll
    for (int c = 0; c < 4; c++) {
      __builtin_amdgcn_global_load_lds((gcp)(Ap + kofs + (size_t)(c * 8) * K),
          (lcp)&As[buf][sb + c * 512], 16, 0, 0);
      __builtin_amdgcn_global_load_lds((gcp)(Bp + kofs + (size_t)(c * 8) * K),
          (lcp)&Bs[buf][sb + c * 512], 16, 0, 0);
    }
  };

  // prologue: 2-deep prefetch
  stage(0, 0);
  stage(1, 64);
  asm volatile("s_waitcnt vmcnt(8)" ::: "memory");   // tile 0 complete
  __builtin_amdgcn_s_barrier();

  for (int t = 0; t < NT; t++) {
    int buf = t & 1;
    bool pf = (t + 2) < NT;
    bf16x8 aF[4][2], bF[4][2];
#pragma unroll
    for (int m = 0; m < 4; m++)
#pragma unroll
      for (int kh = 0; kh < 2; kh++)
        aF[m][kh] = *(const bf16x8*)&As[buf][(wm + m * 16 + l15) * 64 +
                                            ((kh * 4 + quad) ^ r7) * 8];
#pragma unroll
    for (int n = 0; n < 4; n++)
#pragma unroll
      for (int kh = 0; kh < 2; kh++)
        bF[n][kh] = *(const bf16x8*)&Bs[buf][(wn + n * 16 + l15) * 64 +
                                            ((kh * 4 + quad) ^ r7) * 8];
    __builtin_amdgcn_s_setprio(1);
#pragma unroll
    for (int m = 0; m < 4; m++)
#pragma unroll
      for (int n = 0; n < 2; n++)
#pragma unroll
        for (int kh = 0; kh < 2; kh++)
          acc[m][n] = __builtin_amdgcn_mfma_f32_16x16x32_bf16(aF[m][kh], bF[n][kh],
                                                              acc[m][n], 0, 0, 0);
    __builtin_amdgcn_s_setprio(0);
    // all LDS reads of buf complete (lgkmcnt 0) in every wave before anyone overwrites
    asm volatile("s_waitcnt lgkmcnt(0)\n\ts_barrier" ::: "memory");
    if (pf) stage(buf, (t + 2) * 64);   // overwrite cur buf: dead (all frags in regs)
    __builtin_amdgcn_s_setprio(1);
#pragma unroll
    for (int m = 0; m < 4; m++)
#pragma unroll
      for (int n = 2; n < 4; n++)
#pragma unroll
        for (int kh = 0; kh < 2; kh++)
          acc[m][n] = __builtin_amdgcn_mfma_f32_16x16x32_bf16(aF[m][kh], bF[n][kh],
                                                              acc[m][n], 0, 0, 0);
    __builtin_amdgcn_s_setprio(0);
    if (t + 1 < NT) {
      if (pf) asm volatile("s_waitcnt vmcnt(8)" ::: "memory");  // t+1's 8 loads done
      else    asm volatile("s_waitcnt vmcnt(0)" ::: "memory");
      __builtin_amdgcn_s_barrier();
      asm volatile("" ::: "memory");
    }
  }

  // epilogue
#pragma unroll
  for (int am = 0; am < 4; am++)
#pragma unroll
    for (int bn = 0; bn < 4; bn++) {
      int rowi = m0 + wm + am * 16 + quad * 4;
      int col = n0 + wn + bn * 16 + l15;
      float bcol = GELU ? bias[col] : 0.0f;
#pragma unroll
      for (int r = 0; r < 4; r++) {
        float val = acc[am][bn][r] + bcol;
        if (GELU) val = gelu_tanh(val);
        outz[(size_t)(rowi + r) * Nn + col] = f2bf(val);
      }
    }
}

extern "C" void kernel_launch(void* const* d_in, const int* in_sizes, int n_in,
                              void* d_out, int out_size, void* d_ws, size_t ws_size,
                              hipStream_t stream) {
  const float* q = (const float*)d_in[0];
  const float* k = (const float*)d_in[1];
  const float* v = (const float*)d_in[2];
  const float* fc1_w = (const float*)d_in[3];
  const float* fc1_b = (const float*)d_in[4];
  const float* fc2_w = (const float*)d_in[5];
  const float* fc2_b = (const float*)d_in[6];
  const float* ln1_w = (const float*)d_in[7];
  const float* ln1_b = (const float*)d_in[8];
  const float* ln2_w = (const float*)d_in[9];
  const float* ln2_b = (const float*)d_in[10];
  float* out = (float*)d_out;

  char* ws = (char*)d_ws;
  size_t off = 0;
  u16* kb = (u16*)(ws + off); off += (size_t)TT * CC * 2;         // 8 MB
  u16* vtb = (u16*)(ws + off); off += (size_t)TT * CC * 2;        // 8 MB
  u16* w1b = (u16*)(ws + off); off += (size_t)HIDE_ * CC * 2;     // 2 MB
  u16* w2b = (u16*)(ws + off); off += (size_t)CC * HIDE_ * 2;     // 2 MB
  u16* ou = (u16*)(ws + off); off += (size_t)2 * TT * CC * 2;     // 16 MB
  float* lsum = (float*)(ws + off); off += (size_t)2 * TT * HH * 4;  // 512 KB
  u16* q2b = (u16*)(ws + off); off += (size_t)TT * CC * 2;        // 8 MB
  u16* hbuf = (u16*)(ws + off); off += (size_t)TT * HIDE_ * 2;    // 32 MB
  u16* mp = (u16*)(ws + off); off += (size_t)2 * TT * CC * 2;     // 16 MB (split-K 2)

  const float QS = 0.18033688011112042f;   // (1/8) * log2(e)
  prep_kernel<<<4096, 256, 0, stream>>>(k, fc1_w, fc2_w, v, kb, w1b, w2b, vtb);
  attn_kernel<<<dim3(512, 2), 256, 0, stream>>>(q, kb, vtb, ou, lsum, QS);
  ln1_kernel<<<2048, 256, 0, stream>>>(q, ou, lsum, ln1_w, ln1_b, q2b);
  // fc1: M=8192, N=2048, K=512 -> 1024 blocks (gx=16, gy=64), NT=8
  gemm128<true><<<1024, 256, 0, stream>>>(q2b, w1b, fc1_b, hbuf, HIDE_, CC, 8, 16, 64);
  // fc2: M=8192, N=512, K=2048 split-K 2 -> 512 blocks (gx=4, gy=64, z=2), NT=16
  gemm128<false><<<512, 256, 0, stream>>>(hbuf, w2b, fc2_b, mp, CC, HIDE_, 16, 4, 64);
  ln2_kernel<<<2048, 256, 0, stream>>>(q2b, mp, fc2_b, ln2_w, ln2_b, out);
}